// Round 10
// baseline (146.979 us; speedup 1.0000x reference)
//
#include <hip/hip_runtime.h>
#include <hip/hip_bf16.h>
#include <cstdint>
#include <cstddef>

// CRF NLL forward. B=256, T=512, L=64.
// R23: merged-h rewrite. One wave per (batch,chunk) owns all 64 output
// columns (4 independent Jl chains) instead of two h-waves with 2 each.
// Theory: MfmaUtil 40% vs 12% issue-demand -> ~16.7cyc pipe occupancy
// per MFMA = dependent latency; MFMAs don't pipeline for lack of in-wave
// ILP (R21/R22: cross-wave filling null). 4 independent chains/wave give
// back-to-back independent MFMA issue. Bonus: F ds_reads per step halve
// (F is Jl-independent), F-build/fbuf/Areg duplication eliminated.
// Waves 4096->2048 (2/SIMD, 512 blocks). VGPR ~170 -> bounds (256,2).
// LDS 36KB: strans 16KB + scatter 4x8KB (reuse) + fbuf 4KB.
// Verified mappings: Bfr identity Jg=2h+Jl -> Jl; scatter gidx =
// I*1024+(Jl>>1)*512+row*8+4*(Jl&1)+(m16&3) == old global layout;
// pass2 byte-identical input.

constexpr int Bc = 256, Tc = 512, Lc = 64;
#define LOG64F 4.1588830833596715f

typedef __attribute__((ext_vector_type(8))) short v8s;   // 8 bf16
typedef __attribute__((ext_vector_type(4))) float v4f;
typedef __attribute__((ext_vector_type(4))) unsigned int v4u;

__device__ __forceinline__ float lane_bcast(float v, int lane) {
    return __uint_as_float(__builtin_amdgcn_readlane(__float_as_uint(v), lane));
}
__device__ __forceinline__ int lane_bcast_i(int v, int lane) {
    return __builtin_amdgcn_readlane(v, lane);
}
// rounded bf16x2 pack: low16 = bf16(x), high16 = bf16(y). 3 VALU insts.
__device__ __forceinline__ unsigned pk2(float x, float y) {
    const unsigned ux = __float_as_uint(x) + 0x8000u;
    const unsigned uy = __float_as_uint(y) + 0x8000u;
    return __builtin_amdgcn_perm(uy, ux, 0x07060302u);
}
// truncating bf16x2 pack: 1 VALU inst. Used only in the hot chain pack.
__device__ __forceinline__ unsigned pk2t(float x, float y) {
    return __builtin_amdgcn_perm(__float_as_uint(y), __float_as_uint(x), 0x07060302u);
}
__device__ __forceinline__ v8s as_v8s(v4u u) {
    v8s r; __builtin_memcpy(&r, &u, 16); return r;
}
__device__ __forceinline__ unsigned short bf16b(float x) {
    return (unsigned short)((__float_as_uint(x) + 0x8000u) >> 16);
}

// ---------------- Pass 1 ----------------
template<int CH>
__global__ __launch_bounds__(256, 2) void crf_pass1(
    const float* __restrict__ y_true,
    const float* __restrict__ y_pred,
    const float* __restrict__ trans,
    unsigned short* __restrict__ wsm,
    float* __restrict__ wss)
{
    constexpr int S = Tc / CH;            // steps per chunk
    const int tid = threadIdx.x, lane = tid & 63, wv = tid >> 6;
    const int w = blockIdx.x * 4 + wv;    // 0 .. Bc*CH-1
    const int batch = w / CH;
    const int chunk = w % CH;
    const int q = lane >> 4, m16 = lane & 15;
    const int rsub = q, csub = m16;

    __shared__ alignas(16) unsigned char smem_raw[32768];  // strans(16KB), then 4x8KB G scatter
    float* strans = (float*)smem_raw;
    __shared__ alignas(16) float fbuf[4][4][Lc];           // 4 KB, single-buffered

    {   // stage trans with all 256 threads
        const v4f* t4 = (const v4f*)trans;
        #pragma unroll
        for (int k = 0; k < 4; ++k) {
            v4f v = t4[k * 256 + tid];
            *(v4f*)&strans[(k * 256 + tid) * 4] = v;
        }
    }
    __syncthreads();

    // Stationary A operands: Areg[I][K] elem jj = exp(trans[sig][16I+m16]),
    // sig=(jj&3)+4q+16(jj>>2)+32K (verified mapping).
    v8s Areg[4][2];
    #pragma unroll
    for (int I = 0; I < 4; ++I) {
        #pragma unroll
        for (int K = 0; K < 2; ++K) {
            float e[8];
            #pragma unroll
            for (int jj = 0; jj < 8; ++jj) {
                const int sig = (jj & 3) + 4 * q + 16 * (jj >> 2) + 32 * K;
                e[jj] = __expf(strans[sig * Lc + 16 * I + m16]);
            }
            v4u u;
            u.x = pk2(e[0], e[1]); u.y = pk2(e[2], e[3]);
            u.z = pk2(e[4], e[5]); u.w = pk2(e[6], e[7]);
            Areg[I][K] = as_v8s(u);
        }
    }

    const float* yp = y_pred + (size_t)batch * Tc * Lc;
    const float* yt = y_true + (size_t)batch * Tc * Lc;
    const v4f* yp4 = (const v4f*)yp;
    const v4f* yt4 = (const v4f*)yt;

    const int base = chunk * S;           // boundary row
    const int r0 = base + 1;
    float psum = 0.0f, tsum = 0.0f, c = 0.0f;
    int lbl_carry;
    {
        const float bt = yt[base * Lc + lane];
        lbl_carry = (int)__builtin_ctzll(__ballot(bt > 0.5f));
    }

    auto ld4 = [&](const v4f* p, int baseRow) -> v4f {
        int r = baseRow + rsub; r = (r < Tc - 1) ? r : (Tc - 1);
        return p[r * 16 + csub];
    };

    const v4f z4 = {0.f, 0.f, 0.f, 0.f};
    v4f cyp = ld4(yp4, r0), nyp = ld4(yp4, r0 + 4);
    v4f cyt = ld4(yt4, r0), nyt = ld4(yt4, r0 + 4);

    {   // prologue F rows r0..r0+3 (kappa-only; all real rows for every chunk)
        const float k0 = lane_bcast(cyp.x, 0)  + LOG64F;
        const float k1 = lane_bcast(cyp.x, 16) + LOG64F;
        const float k2 = lane_bcast(cyp.x, 32) + LOG64F;
        const float k3 = lane_bcast(cyp.x, 48) + LOG64F;
        c += ((k0 + k1) + (k2 + k3));
        const float kk = (rsub & 1) ? ((rsub & 2) ? k3 : k1)
                                    : ((rsub & 2) ? k2 : k0);
        v4f f;
        f.x = __expf(cyp.x - kk); f.y = __expf(cyp.y - kk);
        f.z = __expf(cyp.z - kk); f.w = __expf(cyp.w - kk);
        *(v4f*)&fbuf[wv][rsub][4 * csub] = f;
    }

    // B = identity columns, Jg = Jl (0..3)
    v8s Bfr[2][4];
    #pragma unroll
    for (int Kc = 0; Kc < 2; ++Kc) {
        #pragma unroll
        for (int Jl = 0; Jl < 4; ++Jl) {
            v8s bb;
            #pragma unroll
            for (int jj = 0; jj < 8; ++jj) {
                const bool one = (m16 == 4 * q + (jj & 3)) &&
                                 (Jl == (jj >> 2) + 2 * Kc);
                bb[jj] = one ? (short)0x3F80 : (short)0;
            }
            Bfr[Kc][Jl] = bb;
        }
    }

    v4f P[4][4];
    #pragma unroll
    for (int I = 0; I < 4; ++I)
        #pragma unroll
        for (int Jl = 0; Jl < 4; ++Jl) P[I][Jl] = z4;

    auto mstep = [&](int s) {
        __builtin_amdgcn_s_setprio(1);
        #pragma unroll
        for (int I = 0; I < 4; ++I) {
            const v4f F = *(const v4f*)&fbuf[wv][s][16 * I + 4 * q];
            #pragma unroll
            for (int Jl = 0; Jl < 4; ++Jl) {
                v4f a = __builtin_amdgcn_mfma_f32_16x16x32_bf16(Areg[I][0], Bfr[0][Jl], z4, 0, 0, 0);
                a = __builtin_amdgcn_mfma_f32_16x16x32_bf16(Areg[I][1], Bfr[1][Jl], a, 0, 0, 0);
                P[I][Jl] = a * F;
            }
        }
        __builtin_amdgcn_s_setprio(0);
        #pragma unroll
        for (int Kc = 0; Kc < 2; ++Kc) {
            #pragma unroll
            for (int Jl = 0; Jl < 4; ++Jl) {
                v4u u;
                u.x = pk2t(P[2 * Kc][Jl].x,     P[2 * Kc][Jl].y);
                u.y = pk2t(P[2 * Kc][Jl].z,     P[2 * Kc][Jl].w);
                u.z = pk2t(P[2 * Kc + 1][Jl].x, P[2 * Kc + 1][Jl].y);
                u.w = pk2t(P[2 * Kc + 1][Jl].z, P[2 * Kc + 1][Jl].w);
                Bfr[Kc][Jl] = as_v8s(u);
            }
        }
    };

    auto scores4 = [&]() {
        psum = fmaf(cyp.x, cyt.x, psum); psum = fmaf(cyp.y, cyt.y, psum);
        psum = fmaf(cyp.z, cyt.z, psum); psum = fmaf(cyp.w, cyt.w, psum);
        const float has = fmaxf(fmaxf(cyt.x, cyt.y), fmaxf(cyt.z, cyt.w));
        int lidx = 0;
        lidx = (cyt.y > 0.5f) ? 1 : lidx;
        lidx = (cyt.z > 0.5f) ? 2 : lidx;
        lidx = (cyt.w > 0.5f) ? 3 : lidx;
        const unsigned long long m = __ballot(has > 0.5f);
        const int ln0 = (int)__builtin_ctz((unsigned)(m & 0xFFFFull));
        const int ln1 = (int)__builtin_ctz((unsigned)((m >> 16) & 0xFFFFull));
        const int ln2 = (int)__builtin_ctz((unsigned)((m >> 32) & 0xFFFFull));
        const int ln3 = (int)__builtin_ctz((unsigned)(m >> 48));
        const int lbl0 = 4 * ln0 + lane_bcast_i(lidx, ln0);
        const int lbl1 = 4 * ln1 + lane_bcast_i(lidx, 16 + ln1);
        const int lbl2 = 4 * ln2 + lane_bcast_i(lidx, 32 + ln2);
        const int lbl3 = 4 * ln3 + lane_bcast_i(lidx, 48 + ln3);
        const int lpA = (rsub & 2) ? lbl1 : lbl_carry;
        const int lpB = (rsub & 2) ? lbl2 : lbl0;
        const int lp  = (rsub & 1) ? lpB : lpA;
        lbl_carry = lbl3;
        const v4f tr = *(const v4f*)&strans[lp * Lc + 4 * csub];
        tsum = fmaf(cyt.x, tr.x, tsum); tsum = fmaf(cyt.y, tr.y, tsum);
        tsum = fmaf(cyt.z, tr.z, tsum); tsum = fmaf(cyt.w, tr.w, tsum);
    };

    #pragma unroll 1
    for (int bi = 0; bi < S / 4 - 1; ++bi) {
        const int rb = r0 + 4 * bi;
        const v4f lyp = ld4(yp4, rb + 8);
        const v4f lyt = ld4(yt4, rb + 8);

        scores4();
        mstep(0); mstep(1); mstep(2); mstep(3);

        {   // postamble: kappa-only F build for rows rb+4..rb+7
            const float k0 = lane_bcast(nyp.x, 0)  + LOG64F;
            const float k1 = lane_bcast(nyp.x, 16) + LOG64F;
            const float k2 = lane_bcast(nyp.x, 32) + LOG64F;
            const float k3 = lane_bcast(nyp.x, 48) + LOG64F;
            c += ((k0 + k1) + k2);
            if (rb + 7 <= Tc - 1) c += k3;          // phantom row-512 guard
            const float kk = (rsub & 1) ? ((rsub & 2) ? k3 : k1)
                                        : ((rsub & 2) ? k2 : k0);
            v4f f;
            f.x = __expf(nyp.x - kk); f.y = __expf(nyp.y - kk);
            f.z = __expf(nyp.z - kk); f.w = __expf(nyp.w - kk);
            *(v4f*)&fbuf[wv][rsub][4 * csub] = f;
        }
        cyp = nyp; nyp = lyp;
        cyt = nyt; nyt = lyt;
    }

    if (chunk < CH - 1) {
        scores4();
        mstep(0); mstep(1); mstep(2); mstep(3);
    } else {
        {   // 3 real tail rows (509..511), rsub3 phantom
            float pd = cyp.x * cyt.x;
            pd = fmaf(cyp.y, cyt.y, pd); pd = fmaf(cyp.z, cyt.z, pd); pd = fmaf(cyp.w, cyt.w, pd);
            const float has = fmaxf(fmaxf(cyt.x, cyt.y), fmaxf(cyt.z, cyt.w));
            int lidx = 0;
            lidx = (cyt.y > 0.5f) ? 1 : lidx;
            lidx = (cyt.z > 0.5f) ? 2 : lidx;
            lidx = (cyt.w > 0.5f) ? 3 : lidx;
            const unsigned long long m = __ballot(has > 0.5f);
            const int ln0 = (int)__builtin_ctz((unsigned)(m & 0xFFFFull));
            const int ln1 = (int)__builtin_ctz((unsigned)((m >> 16) & 0xFFFFull));
            const int lbl0 = 4 * ln0 + lane_bcast_i(lidx, ln0);
            const int lbl1 = 4 * ln1 + lane_bcast_i(lidx, 16 + ln1);
            const int lpA = (rsub & 2) ? lbl1 : lbl_carry;
            const int lp  = (rsub & 1) ? lbl0 : lpA;
            const v4f tr = *(const v4f*)&strans[lp * Lc + 4 * csub];
            float td = cyt.x * tr.x;
            td = fmaf(cyt.y, tr.y, td); td = fmaf(cyt.z, tr.z, td); td = fmaf(cyt.w, tr.w, td);
            if (rsub < 3) { psum += pd; tsum += td; }
        }
        mstep(0); mstep(1); mstep(2);
    }

    // ---- G store in pass2 A-frag order, via LDS scatter (strans now dead) ----
    __syncthreads();   // all waves done reading strans
    unsigned short* myblob = ((unsigned short*)smem_raw) + wv * 4096;
    #pragma unroll
    for (int I = 0; I < 4; ++I) {
        #pragma unroll
        for (int Jl = 0; Jl < 4; ++Jl) {
            float v[4] = {P[I][Jl].x, P[I][Jl].y, P[I][Jl].z, P[I][Jl].w};
            #pragma unroll
            for (int r = 0; r < 4; ++r) {
                const int row = 16 * (m16 >> 2) + 4 * q + r;
                const int gidx = I * 1024 + (Jl >> 1) * 512 + row * 8
                               + 4 * (Jl & 1) + (m16 & 3);
                myblob[gidx] = bf16b(v[r]);
            }
        }
    }
    {   // coalesced copy-out: this wave's 8 KB (layout == global layout)
        const unsigned short* src = myblob + lane * 64;
        unsigned short* dst = wsm + (size_t)(batch * CH + chunk) * 4096 + lane * 64;
        #pragma unroll
        for (int t = 0; t < 8; ++t)
            *(v4u*)(dst + t * 8) = *(const v4u*)(src + t * 8);
    }

    {
        #pragma unroll
        for (int k = 1; k < 64; k <<= 1) psum += __shfl_xor(psum, k);
        #pragma unroll
        for (int k = 1; k < 64; k <<= 1) tsum += __shfl_xor(tsum, k);
        if (lane == 0) {
            float* s = wss + (batch * CH + chunk) * 4;
            s[0] = c; s[1] = psum; s[2] = tsum;
        }
    }
}

// ---------------- Pass 2 ----------------
template<int CH>
__global__ __launch_bounds__(64, 1) void crf_pass2(
    const float* __restrict__ y_true,
    const float* __restrict__ y_pred,
    const unsigned short* __restrict__ wsm,
    const float* __restrict__ wss,
    float* __restrict__ out)
{
    const int lane = threadIdx.x;
    const int b = blockIdx.x;
    const int q = lane >> 4;

    __shared__ float arow[Lc];

    const float* yp = y_pred + (size_t)b * Tc * Lc;
    const float yp0 = yp[lane];
    float psum = yp0 * (((const float*)(y_true + (size_t)b * Tc * Lc))[lane]);
    float tsum = 0.0f;
    float c = lane_bcast(yp0, 0);
    arow[lane] = __expf(yp0 - c);

    v8s Bfr[2];
    #pragma unroll
    for (int cc = 0; cc < 2; ++cc) {
        const v4f lo = *(const v4f*)&arow[32 * cc + 4 * q];
        const v4f hi = *(const v4f*)&arow[32 * cc + 16 + 4 * q];
        v4u u;
        u.x = pk2(lo.x, lo.y); u.y = pk2(lo.z, lo.w);
        u.z = pk2(hi.x, hi.y); u.w = pk2(hi.z, hi.w);
        Bfr[cc] = as_v8s(u);
    }

    const v4f z4 = {0.f, 0.f, 0.f, 0.f};
    v4f P0 = z4, P1 = z4, P2 = z4, P3 = z4;

    v4u Abuf[2][8];
    {
        const v4u* g0 = (const v4u*)(wsm + (size_t)(b * CH) * 4096);
        #pragma unroll
        for (int s = 0; s < 8; ++s) Abuf[0][s] = g0[s * 64 + lane];
    }

    #pragma unroll
    for (int kk = 0; kk < CH; ++kk) {
        const int cur = kk & 1, nxt = cur ^ 1;
        if (kk < CH - 1) {
            const v4u* g1 = (const v4u*)(wsm + (size_t)(b * CH + kk + 1) * 4096);
            #pragma unroll
            for (int s = 0; s < 8; ++s) Abuf[nxt][s] = g1[s * 64 + lane];
        }
        v4f a0 = __builtin_amdgcn_mfma_f32_16x16x32_bf16(as_v8s(Abuf[cur][0]), Bfr[0], z4, 0, 0, 0);
        v4f a1 = __builtin_amdgcn_mfma_f32_16x16x32_bf16(as_v8s(Abuf[cur][2]), Bfr[0], z4, 0, 0, 0);
        v4f a2 = __builtin_amdgcn_mfma_f32_16x16x32_bf16(as_v8s(Abuf[cur][4]), Bfr[0], z4, 0, 0, 0);
        v4f a3 = __builtin_amdgcn_mfma_f32_16x16x32_bf16(as_v8s(Abuf[cur][6]), Bfr[0], z4, 0, 0, 0);
        a0 = __builtin_amdgcn_mfma_f32_16x16x32_bf16(as_v8s(Abuf[cur][1]), Bfr[1], a0, 0, 0, 0);
        a1 = __builtin_amdgcn_mfma_f32_16x16x32_bf16(as_v8s(Abuf[cur][3]), Bfr[1], a1, 0, 0, 0);
        a2 = __builtin_amdgcn_mfma_f32_16x16x32_bf16(as_v8s(Abuf[cur][5]), Bfr[1], a2, 0, 0, 0);
        a3 = __builtin_amdgcn_mfma_f32_16x16x32_bf16(as_v8s(Abuf[cur][7]), Bfr[1], a3, 0, 0, 0);

        const float sc = lane_bcast(a0.x, 0);
        const float inv = 1.0f / sc;
        c += __logf(sc);
        P0 = a0 * inv; P1 = a1 * inv; P2 = a2 * inv; P3 = a3 * inv;
        {
            v4u u;
            u.x = pk2(P0.x, P0.y); u.y = pk2(P0.z, P0.w);
            u.z = pk2(P1.x, P1.y); u.w = pk2(P1.z, P1.w);
            Bfr[0] = as_v8s(u);
        }
        {
            v4u u;
            u.x = pk2(P2.x, P2.y); u.y = pk2(P2.z, P2.w);
            u.z = pk2(P3.x, P3.y); u.w = pk2(P3.z, P3.w);
            Bfr[1] = as_v8s(u);
        }
    }

    float ftot = (((P0.x + P0.y) + (P0.z + P0.w)) + ((P1.x + P1.y) + (P1.z + P1.w)))
               + (((P2.x + P2.y) + (P2.z + P2.w)) + ((P3.x + P3.y) + (P3.z + P3.w)));
    ftot += __shfl_xor(ftot, 16);
    ftot += __shfl_xor(ftot, 32);

    #pragma unroll
    for (int k = 1; k < 64; k <<= 1) psum += __shfl_xor(psum, k);

    if (lane == 0) {
        float cs = c, ps = psum, ts = tsum;
        #pragma unroll
        for (int kk = 0; kk < CH; ++kk) {
            const float* s = wss + (b * CH + kk) * 4;
            cs += s[0]; ps += s[1]; ts += s[2];
        }
        out[b] = -(ps + ts - (cs + __logf(ftot)));
    }
}

extern "C" void kernel_launch(void* const* d_in, const int* in_sizes, int n_in,
                              void* d_out, int out_size, void* d_ws, size_t ws_size,
                              hipStream_t stream) {
    const float* y_true = (const float*)d_in[0];
    const float* y_pred = (const float*)d_in[1];
    const float* trans  = (const float*)d_in[2];
    float* outp = (float*)d_out;
    unsigned short* wsm = (unsigned short*)d_ws;

    // CH=8: G needs 256*8*8KB = 16MB + scalars at +16MB (32KB).
    // Merged-h: one wave per (batch,chunk) -> 2048 waves, 512 blocks.
    float* wss = (float*)((char*)d_ws + (16ull << 20));
    crf_pass1<8><<<dim3(512), dim3(256), 0, stream>>>(y_true, y_pred, trans, wsm, wss);
    crf_pass2<8><<<dim3(256),  dim3(64),  0, stream>>>(y_true, y_pred, wsm, wss, outp);
}

// Round 11
// 143.645 us; speedup vs baseline: 1.0232x; 1.0232x over previous
//
#include <hip/hip_runtime.h>
#include <hip/hip_bf16.h>
#include <cstdint>
#include <cstddef>

// CRF NLL forward. B=256, T=512, L=64.
// R24: pass1 moved from 16x16x32 to 32x32x16 MFMA (2382 vs 2075 TF
// ubench ceiling, +15%; 16 vs 32 MFMA insts/step).
// Evidence for MFMA-bound: R23 cut VALU 15% (VALUBusy 46.5->40.5) at
// FLAT wall; occupancy/stagger/ILP all null; MfmaUtil pinned 39-41%
// across every config; only work-removal and setprio ever paid.
// Mappings: C/D verified (m74/m101): n=l&31, m=(reg&3)+8(reg>>2)+4(l>>5).
// A/B by structural analogy to the session-verified 16x16x32 maps:
// k = (e&3) + 4*(l>>5) + 8*(e>>2), A-row/B-col = l&31.
// Feedback derived register-local: Bfr[2ti+b][tj] elem jj = P[ti][tj][8b+jj].
// G-scatter rewritten as li(to,from) == old layout -> pass2 unchanged.

constexpr int Bc = 256, Tc = 512, Lc = 64;
#define LOG64F 4.1588830833596715f

typedef __attribute__((ext_vector_type(8))) short v8s;    // 8 bf16
typedef __attribute__((ext_vector_type(4))) float v4f;
typedef __attribute__((ext_vector_type(16))) float v16f;  // 32x32 C/D
typedef __attribute__((ext_vector_type(4))) unsigned int v4u;

__device__ __forceinline__ float lane_bcast(float v, int lane) {
    return __uint_as_float(__builtin_amdgcn_readlane(__float_as_uint(v), lane));
}
__device__ __forceinline__ int lane_bcast_i(int v, int lane) {
    return __builtin_amdgcn_readlane(v, lane);
}
// rounded bf16x2 pack: low16 = bf16(x), high16 = bf16(y). 3 VALU insts.
__device__ __forceinline__ unsigned pk2(float x, float y) {
    const unsigned ux = __float_as_uint(x) + 0x8000u;
    const unsigned uy = __float_as_uint(y) + 0x8000u;
    return __builtin_amdgcn_perm(uy, ux, 0x07060302u);
}
// truncating bf16x2 pack: 1 VALU inst. Used only in the hot chain pack.
__device__ __forceinline__ unsigned pk2t(float x, float y) {
    return __builtin_amdgcn_perm(__float_as_uint(y), __float_as_uint(x), 0x07060302u);
}
__device__ __forceinline__ v8s as_v8s(v4u u) {
    v8s r; __builtin_memcpy(&r, &u, 16); return r;
}
__device__ __forceinline__ unsigned short bf16b(float x) {
    return (unsigned short)((__float_as_uint(x) + 0x8000u) >> 16);
}

// ---------------- Pass 1 ----------------
template<int CH>
__global__ __launch_bounds__(256, 2) void crf_pass1(
    const float* __restrict__ y_true,
    const float* __restrict__ y_pred,
    const float* __restrict__ trans,
    unsigned short* __restrict__ wsm,
    float* __restrict__ wss)
{
    constexpr int S = Tc / CH;            // steps per chunk
    const int tid = threadIdx.x, lane = tid & 63, wv = tid >> 6;
    const int w = blockIdx.x * 4 + wv;    // 0 .. Bc*CH-1
    const int batch = w / CH;
    const int chunk = w % CH;
    const int q = lane >> 4, m16 = lane & 15;
    const int rsub = q, csub = m16;
    const int lo5 = lane & 31, lhi = lane >> 5;

    __shared__ alignas(16) unsigned char smem_raw[32768];  // strans(16KB), then 4x8KB G scatter
    float* strans = (float*)smem_raw;
    __shared__ alignas(16) float fbuf[4][4][Lc];           // 4 KB, single-buffered

    {   // stage trans with all 256 threads
        const v4f* t4 = (const v4f*)trans;
        #pragma unroll
        for (int k = 0; k < 4; ++k) {
            v4f v = t4[k * 256 + tid];
            *(v4f*)&strans[(k * 256 + tid) * 4] = v;
        }
    }
    __syncthreads();

    // Stationary A operands (32x32x16): Areg[ti][kc] elem jj =
    // exp(trans[from][to]), from = 16kc + (jj&3)+4*lhi+8*(jj>>2),
    // to = 32ti + lo5.  (k-map by analogy to verified 16x16x32.)
    v8s Areg[2][4];
    #pragma unroll
    for (int ti = 0; ti < 2; ++ti) {
        #pragma unroll
        for (int kc = 0; kc < 4; ++kc) {
            float e[8];
            #pragma unroll
            for (int jj = 0; jj < 8; ++jj) {
                const int from = 16 * kc + (jj & 3) + 4 * lhi + 8 * (jj >> 2);
                const int to   = 32 * ti + lo5;
                e[jj] = __expf(strans[from * Lc + to]);
            }
            v4u u;
            u.x = pk2(e[0], e[1]); u.y = pk2(e[2], e[3]);
            u.z = pk2(e[4], e[5]); u.w = pk2(e[6], e[7]);
            Areg[ti][kc] = as_v8s(u);
        }
    }

    const float* yp = y_pred + (size_t)batch * Tc * Lc;
    const float* yt = y_true + (size_t)batch * Tc * Lc;
    const v4f* yp4 = (const v4f*)yp;
    const v4f* yt4 = (const v4f*)yt;

    const int base = chunk * S;           // boundary row
    const int r0 = base + 1;
    float psum = 0.0f, tsum = 0.0f, c = 0.0f;
    int lbl_carry;
    {
        const float bt = yt[base * Lc + lane];
        lbl_carry = (int)__builtin_ctzll(__ballot(bt > 0.5f));
    }

    auto ld4 = [&](const v4f* p, int baseRow) -> v4f {
        int r = baseRow + rsub; r = (r < Tc - 1) ? r : (Tc - 1);
        return p[r * 16 + csub];
    };

    const v4f z4 = {0.f, 0.f, 0.f, 0.f};
    v4f cyp = ld4(yp4, r0), nyp = ld4(yp4, r0 + 4);
    v4f cyt = ld4(yt4, r0), nyt = ld4(yt4, r0 + 4);

    {   // prologue F rows r0..r0+3 (kappa-only; all real rows for every chunk)
        const float k0 = lane_bcast(cyp.x, 0)  + LOG64F;
        const float k1 = lane_bcast(cyp.x, 16) + LOG64F;
        const float k2 = lane_bcast(cyp.x, 32) + LOG64F;
        const float k3 = lane_bcast(cyp.x, 48) + LOG64F;
        c += ((k0 + k1) + (k2 + k3));
        const float kk = (rsub & 1) ? ((rsub & 2) ? k3 : k1)
                                    : ((rsub & 2) ? k2 : k0);
        v4f f;
        f.x = __expf(cyp.x - kk); f.y = __expf(cyp.y - kk);
        f.z = __expf(cyp.z - kk); f.w = __expf(cyp.w - kk);
        *(v4f*)&fbuf[wv][rsub][4 * csub] = f;
    }

    // B = identity: B[k][n]=1 iff k_global == n_global.
    // k_global = 16kc + (jj&3)+4*lhi+8*(jj>>2); n_global = 32tj + lo5.
    v8s Bfr[4][2];   // [kc][tj]
    #pragma unroll
    for (int kc = 0; kc < 4; ++kc) {
        #pragma unroll
        for (int tj = 0; tj < 2; ++tj) {
            v8s bb;
            #pragma unroll
            for (int jj = 0; jj < 8; ++jj) {
                const int kg = 16 * kc + (jj & 3) + 4 * lhi + 8 * (jj >> 2);
                const int ng = 32 * tj + lo5;
                bb[jj] = (kg == ng) ? (short)0x3F80 : (short)0;
            }
            Bfr[kc][tj] = bb;
        }
    }

    v16f P[2][2];
    #pragma unroll
    for (int ti = 0; ti < 2; ++ti)
        #pragma unroll
        for (int tj = 0; tj < 2; ++tj)
            #pragma unroll
            for (int r = 0; r < 16; ++r) P[ti][tj][r] = 0.f;

    const v16f z16 = P[0][0];

    auto mstep = [&](int s) {
        __builtin_amdgcn_s_setprio(1);
        #pragma unroll
        for (int ti = 0; ti < 2; ++ti) {
            // F for reg-quad rq: rows 32ti + 8rq + 4lhi + {0..3}
            v4f Fv[4];
            #pragma unroll
            for (int rq = 0; rq < 4; ++rq)
                Fv[rq] = *(const v4f*)&fbuf[wv][s][32 * ti + 8 * rq + 4 * lhi];
            #pragma unroll
            for (int tj = 0; tj < 2; ++tj) {
                v16f a = __builtin_amdgcn_mfma_f32_32x32x16_bf16(Areg[ti][0], Bfr[0][tj], z16, 0, 0, 0);
                a = __builtin_amdgcn_mfma_f32_32x32x16_bf16(Areg[ti][1], Bfr[1][tj], a, 0, 0, 0);
                a = __builtin_amdgcn_mfma_f32_32x32x16_bf16(Areg[ti][2], Bfr[2][tj], a, 0, 0, 0);
                a = __builtin_amdgcn_mfma_f32_32x32x16_bf16(Areg[ti][3], Bfr[3][tj], a, 0, 0, 0);
                #pragma unroll
                for (int r = 0; r < 16; ++r)
                    a[r] = a[r] * Fv[r >> 2][r & 3];
                P[ti][tj] = a;
            }
        }
        __builtin_amdgcn_s_setprio(0);
        // pack: Bfr[2ti+b][tj] elem jj = P[ti][tj][8b+jj]
        #pragma unroll
        for (int ti = 0; ti < 2; ++ti) {
            #pragma unroll
            for (int tj = 0; tj < 2; ++tj) {
                #pragma unroll
                for (int b = 0; b < 2; ++b) {
                    v4u u;
                    u.x = pk2t(P[ti][tj][8 * b + 0], P[ti][tj][8 * b + 1]);
                    u.y = pk2t(P[ti][tj][8 * b + 2], P[ti][tj][8 * b + 3]);
                    u.z = pk2t(P[ti][tj][8 * b + 4], P[ti][tj][8 * b + 5]);
                    u.w = pk2t(P[ti][tj][8 * b + 6], P[ti][tj][8 * b + 7]);
                    Bfr[2 * ti + b][tj] = as_v8s(u);
                }
            }
        }
    };

    auto scores4 = [&]() {
        psum = fmaf(cyp.x, cyt.x, psum); psum = fmaf(cyp.y, cyt.y, psum);
        psum = fmaf(cyp.z, cyt.z, psum); psum = fmaf(cyp.w, cyt.w, psum);
        const float has = fmaxf(fmaxf(cyt.x, cyt.y), fmaxf(cyt.z, cyt.w));
        int lidx = 0;
        lidx = (cyt.y > 0.5f) ? 1 : lidx;
        lidx = (cyt.z > 0.5f) ? 2 : lidx;
        lidx = (cyt.w > 0.5f) ? 3 : lidx;
        const unsigned long long m = __ballot(has > 0.5f);
        const int ln0 = (int)__builtin_ctz((unsigned)(m & 0xFFFFull));
        const int ln1 = (int)__builtin_ctz((unsigned)((m >> 16) & 0xFFFFull));
        const int ln2 = (int)__builtin_ctz((unsigned)((m >> 32) & 0xFFFFull));
        const int ln3 = (int)__builtin_ctz((unsigned)(m >> 48));
        const int lbl0 = 4 * ln0 + lane_bcast_i(lidx, ln0);
        const int lbl1 = 4 * ln1 + lane_bcast_i(lidx, 16 + ln1);
        const int lbl2 = 4 * ln2 + lane_bcast_i(lidx, 32 + ln2);
        const int lbl3 = 4 * ln3 + lane_bcast_i(lidx, 48 + ln3);
        const int lpA = (rsub & 2) ? lbl1 : lbl_carry;
        const int lpB = (rsub & 2) ? lbl2 : lbl0;
        const int lp  = (rsub & 1) ? lpB : lpA;
        lbl_carry = lbl3;
        const v4f tr = *(const v4f*)&strans[lp * Lc + 4 * csub];
        tsum = fmaf(cyt.x, tr.x, tsum); tsum = fmaf(cyt.y, tr.y, tsum);
        tsum = fmaf(cyt.z, tr.z, tsum); tsum = fmaf(cyt.w, tr.w, tsum);
    };

    #pragma unroll 1
    for (int bi = 0; bi < S / 4 - 1; ++bi) {
        const int rb = r0 + 4 * bi;
        const v4f lyp = ld4(yp4, rb + 8);
        const v4f lyt = ld4(yt4, rb + 8);

        scores4();
        mstep(0); mstep(1); mstep(2); mstep(3);

        {   // postamble: kappa-only F build for rows rb+4..rb+7
            const float k0 = lane_bcast(nyp.x, 0)  + LOG64F;
            const float k1 = lane_bcast(nyp.x, 16) + LOG64F;
            const float k2 = lane_bcast(nyp.x, 32) + LOG64F;
            const float k3 = lane_bcast(nyp.x, 48) + LOG64F;
            c += ((k0 + k1) + k2);
            if (rb + 7 <= Tc - 1) c += k3;          // phantom row-512 guard
            const float kk = (rsub & 1) ? ((rsub & 2) ? k3 : k1)
                                        : ((rsub & 2) ? k2 : k0);
            v4f f;
            f.x = __expf(nyp.x - kk); f.y = __expf(nyp.y - kk);
            f.z = __expf(nyp.z - kk); f.w = __expf(nyp.w - kk);
            *(v4f*)&fbuf[wv][rsub][4 * csub] = f;
        }
        cyp = nyp; nyp = lyp;
        cyt = nyt; nyt = lyt;
    }

    if (chunk < CH - 1) {
        scores4();
        mstep(0); mstep(1); mstep(2); mstep(3);
    } else {
        {   // 3 real tail rows (509..511), rsub3 phantom
            float pd = cyp.x * cyt.x;
            pd = fmaf(cyp.y, cyt.y, pd); pd = fmaf(cyp.z, cyt.z, pd); pd = fmaf(cyp.w, cyt.w, pd);
            const float has = fmaxf(fmaxf(cyt.x, cyt.y), fmaxf(cyt.z, cyt.w));
            int lidx = 0;
            lidx = (cyt.y > 0.5f) ? 1 : lidx;
            lidx = (cyt.z > 0.5f) ? 2 : lidx;
            lidx = (cyt.w > 0.5f) ? 3 : lidx;
            const unsigned long long m = __ballot(has > 0.5f);
            const int ln0 = (int)__builtin_ctz((unsigned)(m & 0xFFFFull));
            const int ln1 = (int)__builtin_ctz((unsigned)((m >> 16) & 0xFFFFull));
            const int lbl0 = 4 * ln0 + lane_bcast_i(lidx, ln0);
            const int lbl1 = 4 * ln1 + lane_bcast_i(lidx, 16 + ln1);
            const int lpA = (rsub & 2) ? lbl1 : lbl_carry;
            const int lp  = (rsub & 1) ? lbl0 : lpA;
            const v4f tr = *(const v4f*)&strans[lp * Lc + 4 * csub];
            float td = cyt.x * tr.x;
            td = fmaf(cyt.y, tr.y, td); td = fmaf(cyt.z, tr.z, td); td = fmaf(cyt.w, tr.w, td);
            if (rsub < 3) { psum += pd; tsum += td; }
        }
        mstep(0); mstep(1); mstep(2);
    }

    // ---- G store in pass2 A-frag order, via LDS scatter (strans now dead) ----
    // li(to,fr) = (to>>4)*1024 + (fr>>5)*512 + (16*((fr&15)>>2)+(to&15))*8
    //           + 4*((fr>>4)&1) + (fr&3)   [== verified 16x16 layout]
    __syncthreads();   // all waves done reading strans
    unsigned short* myblob = ((unsigned short*)smem_raw) + wv * 4096;
    #pragma unroll
    for (int ti = 0; ti < 2; ++ti) {
        #pragma unroll
        for (int tj = 0; tj < 2; ++tj) {
            #pragma unroll
            for (int r = 0; r < 16; ++r) {
                const int to = 32 * ti + (r & 3) + 8 * (r >> 2) + 4 * lhi;
                const int fr = 32 * tj + lo5;
                const int li = (to >> 4) * 1024 + (fr >> 5) * 512
                             + (16 * ((fr & 15) >> 2) + (to & 15)) * 8
                             + 4 * ((fr >> 4) & 1) + (fr & 3);
                myblob[li] = bf16b(P[ti][tj][r]);
            }
        }
    }
    {   // coalesced copy-out: this wave's 8 KB (layout == global layout)
        const unsigned short* src = myblob + lane * 64;
        unsigned short* dst = wsm + (size_t)(batch * CH + chunk) * 4096 + lane * 64;
        #pragma unroll
        for (int t = 0; t < 8; ++t)
            *(v4u*)(dst + t * 8) = *(const v4u*)(src + t * 8);
    }

    {
        #pragma unroll
        for (int k = 1; k < 64; k <<= 1) psum += __shfl_xor(psum, k);
        #pragma unroll
        for (int k = 1; k < 64; k <<= 1) tsum += __shfl_xor(tsum, k);
        if (lane == 0) {
            float* s = wss + (batch * CH + chunk) * 4;
            s[0] = c; s[1] = psum; s[2] = tsum;
        }
    }
}

// ---------------- Pass 2 ----------------
template<int CH>
__global__ __launch_bounds__(64, 1) void crf_pass2(
    const float* __restrict__ y_true,
    const float* __restrict__ y_pred,
    const unsigned short* __restrict__ wsm,
    const float* __restrict__ wss,
    float* __restrict__ out)
{
    const int lane = threadIdx.x;
    const int b = blockIdx.x;
    const int q = lane >> 4;

    __shared__ float arow[Lc];

    const float* yp = y_pred + (size_t)b * Tc * Lc;
    const float yp0 = yp[lane];
    float psum = yp0 * (((const float*)(y_true + (size_t)b * Tc * Lc))[lane]);
    float tsum = 0.0f;
    float c = lane_bcast(yp0, 0);
    arow[lane] = __expf(yp0 - c);

    v8s Bfr[2];
    #pragma unroll
    for (int cc = 0; cc < 2; ++cc) {
        const v4f lo = *(const v4f*)&arow[32 * cc + 4 * q];
        const v4f hi = *(const v4f*)&arow[32 * cc + 16 + 4 * q];
        v4u u;
        u.x = pk2(lo.x, lo.y); u.y = pk2(lo.z, lo.w);
        u.z = pk2(hi.x, hi.y); u.w = pk2(hi.z, hi.w);
        Bfr[cc] = as_v8s(u);
    }

    const v4f z4 = {0.f, 0.f, 0.f, 0.f};
    v4f P0 = z4, P1 = z4, P2 = z4, P3 = z4;

    v4u Abuf[2][8];
    {
        const v4u* g0 = (const v4u*)(wsm + (size_t)(b * CH) * 4096);
        #pragma unroll
        for (int s = 0; s < 8; ++s) Abuf[0][s] = g0[s * 64 + lane];
    }

    #pragma unroll
    for (int kk = 0; kk < CH; ++kk) {
        const int cur = kk & 1, nxt = cur ^ 1;
        if (kk < CH - 1) {
            const v4u* g1 = (const v4u*)(wsm + (size_t)(b * CH + kk + 1) * 4096);
            #pragma unroll
            for (int s = 0; s < 8; ++s) Abuf[nxt][s] = g1[s * 64 + lane];
        }
        v4f a0 = __builtin_amdgcn_mfma_f32_16x16x32_bf16(as_v8s(Abuf[cur][0]), Bfr[0], z4, 0, 0, 0);
        v4f a1 = __builtin_amdgcn_mfma_f32_16x16x32_bf16(as_v8s(Abuf[cur][2]), Bfr[0], z4, 0, 0, 0);
        v4f a2 = __builtin_amdgcn_mfma_f32_16x16x32_bf16(as_v8s(Abuf[cur][4]), Bfr[0], z4, 0, 0, 0);
        v4f a3 = __builtin_amdgcn_mfma_f32_16x16x32_bf16(as_v8s(Abuf[cur][6]), Bfr[0], z4, 0, 0, 0);
        a0 = __builtin_amdgcn_mfma_f32_16x16x32_bf16(as_v8s(Abuf[cur][1]), Bfr[1], a0, 0, 0, 0);
        a1 = __builtin_amdgcn_mfma_f32_16x16x32_bf16(as_v8s(Abuf[cur][3]), Bfr[1], a1, 0, 0, 0);
        a2 = __builtin_amdgcn_mfma_f32_16x16x32_bf16(as_v8s(Abuf[cur][5]), Bfr[1], a2, 0, 0, 0);
        a3 = __builtin_amdgcn_mfma_f32_16x16x32_bf16(as_v8s(Abuf[cur][7]), Bfr[1], a3, 0, 0, 0);

        const float sc = lane_bcast(a0.x, 0);
        const float inv = 1.0f / sc;
        c += __logf(sc);
        P0 = a0 * inv; P1 = a1 * inv; P2 = a2 * inv; P3 = a3 * inv;
        {
            v4u u;
            u.x = pk2(P0.x, P0.y); u.y = pk2(P0.z, P0.w);
            u.z = pk2(P1.x, P1.y); u.w = pk2(P1.z, P1.w);
            Bfr[0] = as_v8s(u);
        }
        {
            v4u u;
            u.x = pk2(P2.x, P2.y); u.y = pk2(P2.z, P2.w);
            u.z = pk2(P3.x, P3.y); u.w = pk2(P3.z, P3.w);
            Bfr[1] = as_v8s(u);
        }
    }

    float ftot = (((P0.x + P0.y) + (P0.z + P0.w)) + ((P1.x + P1.y) + (P1.z + P1.w)))
               + (((P2.x + P2.y) + (P2.z + P2.w)) + ((P3.x + P3.y) + (P3.z + P3.w)));
    ftot += __shfl_xor(ftot, 16);
    ftot += __shfl_xor(ftot, 32);

    #pragma unroll
    for (int k = 1; k < 64; k <<= 1) psum += __shfl_xor(psum, k);

    if (lane == 0) {
        float cs = c, ps = psum, ts = tsum;
        #pragma unroll
        for (int kk = 0; kk < CH; ++kk) {
            const float* s = wss + (b * CH + kk) * 4;
            cs += s[0]; ps += s[1]; ts += s[2];
        }
        out[b] = -(ps + ts - (cs + __logf(ftot)));
    }
}

extern "C" void kernel_launch(void* const* d_in, const int* in_sizes, int n_in,
                              void* d_out, int out_size, void* d_ws, size_t ws_size,
                              hipStream_t stream) {
    const float* y_true = (const float*)d_in[0];
    const float* y_pred = (const float*)d_in[1];
    const float* trans  = (const float*)d_in[2];
    float* outp = (float*)d_out;
    unsigned short* wsm = (unsigned short*)d_ws;

    // CH=8: G needs 256*8*8KB = 16MB + scalars at +16MB (32KB).
    float* wss = (float*)((char*)d_ws + (16ull << 20));
    crf_pass1<8><<<dim3(512), dim3(256), 0, stream>>>(y_true, y_pred, trans, wsm, wss);
    crf_pass2<8><<<dim3(256),  dim3(64),  0, stream>>>(y_true, y_pred, wsm, wss, outp);
}